// Round 1
// 261.516 us; speedup vs baseline: 1.0288x; 1.0288x over previous
//
#include <hip/hip_runtime.h>
#include <math.h>

// Problem constants (fixed by setup_inputs): B=16, T=4096, D=512, fp32.
#define BB 16
#define TT 4096
#define DD 512
#define D4 128   // DD / 4 (float4 columns)

typedef float v4f __attribute__((ext_vector_type(4)));

__device__ __forceinline__ float sigmf(float v) {
    return 1.0f / (1.0f + expf(-v));
}

// Nontemporal float4 store: out is write-once/never-read; keep it from
// evicting x out of the 256 MB Infinity Cache between pass 1 and pass 2.
__device__ __forceinline__ void nt_store4(float4* p, const float4& s) {
    __builtin_nontemporal_store(*reinterpret_cast<const v4f*>(&s),
                                reinterpret_cast<v4f*>(p));
}

// K1: per-(b, chunk) local scan with zero init (chunk 0: exact init s_{-1}=x0),
// writes only the chunk-end value E_c to `ends`.
// Block: 256 threads = 2 b-rows x 128 float4 columns. Grid: (C, BB/2).
__global__ __launch_bounds__(256) void es_chunk_ends(
    const float* __restrict__ x, const float* __restrict__ alpha,
    float* __restrict__ ends, int C, int L)
{
    const int c   = blockIdx.x;
    const int tid = threadIdx.x;
    const int b   = (blockIdx.y << 1) + (tid >> 7);
    const int d4  = tid & 127;

    const float4 al = reinterpret_cast<const float4*>(alpha)[d4];
    const float ax = sigmf(al.x), ay = sigmf(al.y), az = sigmf(al.z), aw = sigmf(al.w);
    const float fx = 1.0f - ax, fy = 1.0f - ay, fz = 1.0f - az, fw = 1.0f - aw;

    const float4* xp = reinterpret_cast<const float4*>(x)
                     + ((size_t)b * TT + (size_t)c * L) * D4 + d4;

    float4 s;
    if (c == 0) {
        s = xp[0];                       // virtual s_{-1} = x_0 -> chunk 0 end is exact
    } else {
        s.x = s.y = s.z = s.w = 0.0f;    // zero-init local scan
    }

    #pragma unroll 8
    for (int i = 0; i < L; ++i) {
        const float4 v = xp[(size_t)i * D4];
        s.x = fmaf(ax, v.x, fx * s.x);
        s.y = fmaf(ay, v.y, fy * s.y);
        s.z = fmaf(az, v.z, fz * s.z);
        s.w = fmaf(aw, v.w, fw * s.w);
    }

    reinterpret_cast<float4*>(ends)[((size_t)b * C + c) * D4 + d4] = s;
}

// K2' (fused): each block redundantly computes the carry S_{c-1} for its own
// chunk by scanning E_0..E_{c-1} (ascending, same op order as the old K2 so
// numerics are bit-identical), then re-reads its x chunk (L3-resident after
// K1) starting from the exact carry and writes the output with NT stores.
// Replaces the old 8-block serial carry kernel (3% occupancy, cross-XCD
// latency-bound) + one kernel-launch boundary.
__global__ __launch_bounds__(256) void es_final_fused(
    const float* __restrict__ x, const float* __restrict__ alpha,
    const float* __restrict__ ends, float* __restrict__ out, int C, int L)
{
    const int c   = blockIdx.x;
    const int tid = threadIdx.x;
    const int b   = (blockIdx.y << 1) + (tid >> 7);
    const int d4  = tid & 127;

    const float4 al = reinterpret_cast<const float4*>(alpha)[d4];
    const float ax = sigmf(al.x), ay = sigmf(al.y), az = sigmf(al.z), aw = sigmf(al.w);
    const float fx = 1.0f - ax, fy = 1.0f - ay, fz = 1.0f - az, fw = 1.0f - aw;

    const size_t base = ((size_t)b * TT + (size_t)c * L) * D4 + d4;
    const float4* xp = reinterpret_cast<const float4*>(x) + base;
    float4*       op = reinterpret_cast<float4*>(out) + base;

    float4 s;
    if (c == 0) {
        s = xp[0];                       // s_{-1} = x_0 (exact)
    } else {
        // Redundant per-block carry scan: S = E_0; S = fma(fL, S, E_j), j ascending.
        float4 fL;
        fL.x = powf(fx, (float)L);
        fL.y = powf(fy, (float)L);
        fL.z = powf(fz, (float)L);
        fL.w = powf(fw, (float)L);

        const float4* e = reinterpret_cast<const float4*>(ends)
                        + (size_t)b * C * D4 + d4;

        float4 S = e[0];                 // S_0 = E_0 (already exact)
        int j = 1;
        for (; j + 8 <= c; j += 8) {     // 8-deep prefetch: loads are independent
            float4 v[8];
            #pragma unroll
            for (int k = 0; k < 8; ++k) v[k] = e[(size_t)(j + k) * D4];
            #pragma unroll
            for (int k = 0; k < 8; ++k) {
                S.x = fmaf(fL.x, S.x, v[k].x);
                S.y = fmaf(fL.y, S.y, v[k].y);
                S.z = fmaf(fL.z, S.z, v[k].z);
                S.w = fmaf(fL.w, S.w, v[k].w);
            }
        }
        for (; j < c; ++j) {
            const float4 v = e[(size_t)j * D4];
            S.x = fmaf(fL.x, S.x, v.x);
            S.y = fmaf(fL.y, S.y, v.y);
            S.z = fmaf(fL.z, S.z, v.z);
            S.w = fmaf(fL.w, S.w, v.w);
        }
        s = S;                           // exact S_{c-1}
    }

    #pragma unroll 8
    for (int i = 0; i < L; ++i) {
        const float4 v = xp[(size_t)i * D4];
        s.x = fmaf(ax, v.x, fx * s.x);
        s.y = fmaf(ay, v.y, fy * s.y);
        s.z = fmaf(az, v.z, fz * s.z);
        s.w = fmaf(aw, v.w, fw * s.w);
        nt_store4(op + (size_t)i * D4, s);
    }
}

// Fallback: full serial scan per (b, d4) column if ws is too small for chunking.
__global__ __launch_bounds__(256) void es_serial(
    const float* __restrict__ x, const float* __restrict__ alpha,
    float* __restrict__ out)
{
    const int g  = blockIdx.x * 256 + threadIdx.x;   // 0..2047
    const int b  = g >> 7;
    const int d4 = g & 127;

    const float4 al = reinterpret_cast<const float4*>(alpha)[d4];
    const float ax = sigmf(al.x), ay = sigmf(al.y), az = sigmf(al.z), aw = sigmf(al.w);
    const float fx = 1.0f - ax, fy = 1.0f - ay, fz = 1.0f - az, fw = 1.0f - aw;

    const float4* xp = reinterpret_cast<const float4*>(x) + (size_t)b * TT * D4 + d4;
    float4*       op = reinterpret_cast<float4*>(out) + (size_t)b * TT * D4 + d4;

    float4 s = xp[0];
    #pragma unroll 4
    for (int t = 0; t < TT; ++t) {
        const float4 v = xp[(size_t)t * D4];
        s.x = fmaf(ax, v.x, fx * s.x);
        s.y = fmaf(ay, v.y, fy * s.y);
        s.z = fmaf(az, v.z, fz * s.z);
        s.w = fmaf(aw, v.w, fw * s.w);
        op[(size_t)t * D4] = s;
    }
}

extern "C" void kernel_launch(void* const* d_in, const int* in_sizes, int n_in,
                              void* d_out, int out_size, void* d_ws, size_t ws_size,
                              hipStream_t stream)
{
    const float* x     = (const float*)d_in[0];
    const float* alpha = (const float*)d_in[1];
    float*       out   = (float*)d_out;

    // Pick chunk count C (pow2, >=8) so the carry buffer fits in workspace.
    int C = 128;
    while (C > 8 && (size_t)BB * C * DD * sizeof(float) > ws_size) C >>= 1;

    if ((size_t)BB * C * DD * sizeof(float) > ws_size) {
        // Workspace too small even for C=8: serial fallback (correct, slower).
        es_serial<<<dim3(8), 256, 0, stream>>>(x, alpha, out);
        return;
    }

    const int L = TT / C;
    float* ends = (float*)d_ws;

    es_chunk_ends<<<dim3(C, BB / 2), 256, 0, stream>>>(x, alpha, ends, C, L);
    es_final_fused<<<dim3(C, BB / 2), 256, 0, stream>>>(x, alpha, ends, out, C, L);
}